// Round 1
// baseline (2822.983 us; speedup 1.0000x reference)
//
#include <hip/hip_runtime.h>
#include <stdint.h>

#define B      256
#define DIN    700
#define T      250
#define H      1024
#define DOUT   20
#define NW_IN  11     // u64 words for 700 input bits
#define NW_INP 12     // padded
#define NW_H   16     // u64 words for 1024 hidden bits

typedef unsigned long long u64;

// ---------------- prep: transpose weights ----------------
// blocks [0,2800): Wt[d][h] = W_hid[h][d]   (716800 elems)
// blocks [2800,2880): WoT[h][o] = W_out[o][h] (20480 elems)
__global__ void prep_weights(const float* __restrict__ W_hid,
                             const float* __restrict__ W_out,
                             float* __restrict__ Wt,
                             float* __restrict__ WoT) {
    int idx = blockIdx.x * 256 + threadIdx.x;
    if (blockIdx.x < 2800) {
        int d = idx / H;
        int h = idx - d * H;
        Wt[idx] = W_hid[h * DIN + d];
    } else {
        int i = idx - 2800 * 256;   // 0..20479
        int h = i / DOUT;
        int o = i - h * DOUT;
        WoT[i] = W_out[o * H + h];
    }
}

// ---------------- prep: bitpack spikes ----------------
// bits[b][t][w] : bit j of word w = (spike_data[b][64w+j][t] > 0.5)
// grid = 1024 blocks: b = blk/4, word-chunk wc = blk%4 (words 3wc..)
__global__ void prep_bits(const float* __restrict__ spk,
                          u64* __restrict__ bits) {
    int b  = blockIdx.x >> 2;
    int wc = blockIdx.x & 3;
    int t  = threadIdx.x;
    if (t >= T) return;
    int w0 = wc * 3;
    int w1 = (wc == 3) ? NW_IN : w0 + 3;
    const float* base = spk + (size_t)b * DIN * T + t;
    for (int w = w0; w < w1; ++w) {
        u64 m = 0;
#pragma unroll
        for (int j = 0; j < 64; ++j) {
            int d = (w << 6) + j;
            if (d < DIN) {
                float x = base[(size_t)d * T];
                m |= (u64)(x > 0.5f) << j;
            }
        }
        bits[((size_t)b * T + t) * NW_INP + w] = m;
    }
}

// ---------------- hidden layer: sparse gather + scan ----------------
// one block per b, thread = h (1024 threads, 16 waves). No barriers.
__global__ void __launch_bounds__(1024)
hidden_kernel(const u64* __restrict__ bits,
              const float* __restrict__ Wt,
              const float* __restrict__ hs0,
              const float* __restrict__ hv0,
              u64* __restrict__ hsbits) {
    int b = blockIdx.x;
    int h = threadIdx.x;
    int wv = h >> 6;

    float hv0v = hv0[b * H + h];
    float sp0  = hs0[b * H + h];
    float keep = hv0v * 0.5f * (1.0f - sp0);

    const u64* bb = bits + (size_t)b * T * NW_INP;

    for (int t = 0; t < T; ++t) {
        const u64* wp = bb + (size_t)t * NW_INP;
        float cur = 0.0f;
#pragma unroll
        for (int w = 0; w < NW_IN; ++w) {
            u64 m = wp[w];           // wave-uniform broadcast load (L1)
            int dbase = w << 6;
            while (m) {
                int j = __builtin_ctzll(m);
                m &= m - 1;
                cur += Wt[(size_t)(dbase + j) * H + h];   // coalesced 4KB/row
            }
        }
        float hv = keep + cur;
        bool s = hv > 0.5f;
        keep = s ? 0.0f : hv * 0.5f;
        u64 ball = __ballot(s);
        if ((h & 63) == 0)
            hsbits[((size_t)b * T + t) * NW_H + wv] = ball;
    }
}

// ---------------- output currents: Iout[b*T+t][o] ----------------
// one wave per row (b,t); lanes 0..19 = outputs, bitscan active h.
__global__ void out_currents(const u64* __restrict__ hsbits,
                             const float* __restrict__ WoT,
                             float* __restrict__ Iout) {
    int wv   = threadIdx.x >> 6;
    int lane = threadIdx.x & 63;
    int row  = blockIdx.x * 4 + wv;   // < 64000 exactly

    u64 myw = 0;
    if (lane < NW_H) myw = hsbits[(size_t)row * NW_H + lane];

    float acc = 0.0f;
#pragma unroll
    for (int w = 0; w < NW_H; ++w) {
        u64 m = __shfl(myw, w);       // broadcast word w to all lanes
        int hbase = w << 6;
        while (m) {
            int j = __builtin_ctzll(m);
            m &= m - 1;
            if (lane < DOUT)
                acc += WoT[(size_t)(hbase + j) * DOUT + lane];
        }
    }
    if (lane < DOUT) Iout[(size_t)row * DOUT + lane] = acc;
}

// ---------------- output scan + spike count ----------------
__global__ void out_scan(const float* __restrict__ Iout,
                         const float* __restrict__ os0,
                         const float* __restrict__ ov0,
                         float* __restrict__ outp) {
    int idx = blockIdx.x * 256 + threadIdx.x;
    if (idx >= B * DOUT) return;
    int b = idx / DOUT;
    int o = idx - b * DOUT;

    float ov = ov0[idx];
    float os = os0[idx];
    float keep = ov * 0.5f * (1.0f - os);
    float cnt = 0.0f;
    const float* ip = Iout + (size_t)b * T * DOUT + o;
#pragma unroll 5
    for (int t = 0; t < T; ++t) {
        float v = keep + ip[(size_t)t * DOUT];
        float s = (v > 0.5f) ? 1.0f : 0.0f;
        cnt += s;
        keep = v * 0.5f * (1.0f - s);
    }
    outp[idx] = cnt;
}

extern "C" void kernel_launch(void* const* d_in, const int* in_sizes, int n_in,
                              void* d_out, int out_size, void* d_ws, size_t ws_size,
                              hipStream_t stream) {
    const float* spike = (const float*)d_in[0];   // [256][700][250]
    const float* W_hid = (const float*)d_in[1];   // [1024][700]
    const float* W_out = (const float*)d_in[2];   // [20][1024]
    const float* hs0   = (const float*)d_in[3];   // [256][1024]
    const float* hv0   = (const float*)d_in[4];
    const float* os0   = (const float*)d_in[5];   // [256][20]
    const float* ov0   = (const float*)d_in[6];
    float* outp = (float*)d_out;                  // [256][20]

    // workspace layout (all multiples of 1024 B)
    char* ws = (char*)d_ws;
    float* Wt     = (float*)(ws);                               // 2,867,200 B
    float* WoT    = (float*)(ws + 2867200);                     //    81,920 B
    u64*   bits   = (u64*)  (ws + 2949120);                     // 6,144,000 B
    u64*   hsbits = (u64*)  (ws + 9093120);                     // 8,192,000 B
    float* Iout   = (float*)(ws + 17285120);                    // 5,120,000 B
    // total ~22.4 MB

    prep_weights<<<2880, 256, 0, stream>>>(W_hid, W_out, Wt, WoT);
    prep_bits<<<1024, 256, 0, stream>>>(spike, bits);
    hidden_kernel<<<B, 1024, 0, stream>>>(bits, Wt, hs0, hv0, hsbits);
    out_currents<<<16000, 256, 0, stream>>>(hsbits, WoT, Iout);
    out_scan<<<20, 256, 0, stream>>>(Iout, os0, ov0, outp);
}

// Round 2
// 1305.704 us; speedup vs baseline: 2.1620x; 2.1620x over previous
//
#include <hip/hip_runtime.h>
#include <stdint.h>

#define B      256
#define DIN    700
#define T      250
#define H      1024
#define DOUT   20
#define NW_IN  11     // u64 words for 700 input bits
#define NW_INP 12     // padded
#define NW_H   16     // u64 words for 1024 hidden bits

typedef unsigned long long u64;

// ---------------- prep: transpose weights ----------------
__global__ void prep_weights(const float* __restrict__ W_hid,
                             const float* __restrict__ W_out,
                             float* __restrict__ Wt,
                             float* __restrict__ WoT) {
    int idx = blockIdx.x * 256 + threadIdx.x;
    if (blockIdx.x < 2800) {
        int d = idx / H;
        int h = idx - d * H;
        Wt[idx] = W_hid[h * DIN + d];
    } else {
        int i = idx - 2800 * 256;   // 0..20479
        int h = i / DOUT;
        int o = i - h * DOUT;
        WoT[i] = W_out[o * H + h];
    }
}

// ---------------- prep: bitpack spikes ----------------
__global__ void prep_bits(const float* __restrict__ spk,
                          u64* __restrict__ bits) {
    int b  = blockIdx.x >> 2;
    int wc = blockIdx.x & 3;
    int t  = threadIdx.x;
    if (t >= T) return;
    int w0 = wc * 3;
    int w1 = (wc == 3) ? NW_IN : w0 + 3;
    const float* base = spk + (size_t)b * DIN * T + t;
    for (int w = w0; w < w1; ++w) {
        u64 m = 0;
#pragma unroll
        for (int j = 0; j < 64; ++j) {
            int d = (w << 6) + j;
            if (d < DIN) {
                float x = base[(size_t)d * T];
                m |= (u64)(x > 0.5f) << j;
            }
        }
        bits[((size_t)b * T + t) * NW_INP + w] = m;
    }
}

// ---------------- hidden layer: LDS index-list gather + scan ----------------
// one block per b, thread = h (1024 threads, 16 waves).
// Per t: ordered expansion of active input indices into LDS (ascending d,
// matching R1's summation order), then unrolled-by-8 independent gathers.
// Double-buffered list -> ONE barrier per t (write(t+2) is after barrier(t+1),
// which every thread reaches only after finishing gather(t)).
__global__ void __launch_bounds__(1024)
hidden_kernel(const u64* __restrict__ bits,
              const float* __restrict__ Wt,
              const float* __restrict__ hs0,
              const float* __restrict__ hv0,
              u64* __restrict__ hsbits) {
    __shared__ int idx_l[2][256];

    int b = blockIdx.x;
    int h = threadIdx.x;
    int wv   = h >> 6;
    int lane = h & 63;

    float keep = hv0[b * H + h] * 0.5f * (1.0f - hs0[b * H + h]);

    const u64* bb = bits + (size_t)b * T * NW_INP;

    for (int t = 0; t < T; ++t) {
        const u64* wp = bb + (size_t)t * NW_INP;
        u64 w[NW_IN];
#pragma unroll
        for (int k = 0; k < NW_IN; ++k) w[k] = wp[k];

        int base[NW_IN + 1];
        base[0] = 0;
#pragma unroll
        for (int k = 0; k < NW_IN; ++k) base[k + 1] = base[k] + __popcll(w[k]);
        int n = base[NW_IN];

        int buf = t & 1;
        if (wv < NW_IN) {
            u64 m = w[wv];
            if ((m >> lane) & 1ull) {
                int pos = base[wv] + __popcll(m & ((1ull << lane) - 1ull));
                idx_l[buf][pos] = (wv << 6) + lane;
            }
        }
        __syncthreads();

        const int* il = idx_l[buf];
        float cur = 0.0f;
        int i = 0;
        for (; i + 8 <= n; i += 8) {
            int j0 = il[i + 0], j1 = il[i + 1], j2 = il[i + 2], j3 = il[i + 3];
            int j4 = il[i + 4], j5 = il[i + 5], j6 = il[i + 6], j7 = il[i + 7];
            float v0 = Wt[(size_t)j0 * H + h];
            float v1 = Wt[(size_t)j1 * H + h];
            float v2 = Wt[(size_t)j2 * H + h];
            float v3 = Wt[(size_t)j3 * H + h];
            float v4 = Wt[(size_t)j4 * H + h];
            float v5 = Wt[(size_t)j5 * H + h];
            float v6 = Wt[(size_t)j6 * H + h];
            float v7 = Wt[(size_t)j7 * H + h];
            cur += v0; cur += v1; cur += v2; cur += v3;
            cur += v4; cur += v5; cur += v6; cur += v7;
        }
        for (; i < n; ++i) cur += Wt[(size_t)il[i] * H + h];

        float hv = keep + cur;
        bool s = hv > 0.5f;
        keep = s ? 0.0f : hv * 0.5f;
        u64 ball = __ballot(s);
        if (lane == 0)
            hsbits[((size_t)b * T + t) * NW_H + wv] = ball;
    }
}

// ---------------- output currents: Iout[b*T+t][o] ----------------
// one wave per row (b,t); process 16 hidden-bit words in 4 groups of 4,
// per-wave LDS index list (double-buffered), unrolled-by-4 gathers on 20 lanes.
__global__ void __launch_bounds__(256)
out_currents(const u64* __restrict__ hsbits,
             const float* __restrict__ WoT,
             float* __restrict__ Iout) {
    __shared__ int lidx[4][2][256];

    int wv   = threadIdx.x >> 6;
    int lane = threadIdx.x & 63;
    int row  = blockIdx.x * 4 + wv;   // < 64000 exactly

    const u64* wp = hsbits + (size_t)row * NW_H;

    float acc = 0.0f;
#pragma unroll
    for (int g = 0; g < 4; ++g) {
        u64 w[4];
#pragma unroll
        for (int k = 0; k < 4; ++k) w[k] = wp[g * 4 + k];

        int base[5];
        base[0] = 0;
#pragma unroll
        for (int k = 0; k < 4; ++k) base[k + 1] = base[k] + __popcll(w[k]);
        int n = base[4];

        int buf = g & 1;
#pragma unroll
        for (int k = 0; k < 4; ++k) {
            u64 m = w[k];
            if ((m >> lane) & 1ull) {
                int pos = base[k] + __popcll(m & ((1ull << lane) - 1ull));
                lidx[wv][buf][pos] = ((g * 4 + k) << 6) + lane;
            }
        }
        __syncthreads();

        const int* il = lidx[wv][buf];
        int i = 0;
        for (; i + 4 <= n; i += 4) {
            int j0 = il[i + 0], j1 = il[i + 1], j2 = il[i + 2], j3 = il[i + 3];
            if (lane < DOUT) {
                float v0 = WoT[(size_t)j0 * DOUT + lane];
                float v1 = WoT[(size_t)j1 * DOUT + lane];
                float v2 = WoT[(size_t)j2 * DOUT + lane];
                float v3 = WoT[(size_t)j3 * DOUT + lane];
                acc += v0; acc += v1; acc += v2; acc += v3;
            }
        }
        for (; i < n; ++i) {
            if (lane < DOUT) acc += WoT[(size_t)il[i] * DOUT + lane];
        }
    }
    if (lane < DOUT) Iout[(size_t)row * DOUT + lane] = acc;
}

// ---------------- output scan + spike count ----------------
__global__ void out_scan(const float* __restrict__ Iout,
                         const float* __restrict__ os0,
                         const float* __restrict__ ov0,
                         float* __restrict__ outp) {
    int idx = blockIdx.x * 256 + threadIdx.x;
    if (idx >= B * DOUT) return;
    int b = idx / DOUT;
    int o = idx - b * DOUT;

    float ov = ov0[idx];
    float os = os0[idx];
    float keep = ov * 0.5f * (1.0f - os);
    float cnt = 0.0f;
    const float* ip = Iout + (size_t)b * T * DOUT + o;
#pragma unroll 5
    for (int t = 0; t < T; ++t) {
        float v = keep + ip[(size_t)t * DOUT];
        float s = (v > 0.5f) ? 1.0f : 0.0f;
        cnt += s;
        keep = v * 0.5f * (1.0f - s);
    }
    outp[idx] = cnt;
}

extern "C" void kernel_launch(void* const* d_in, const int* in_sizes, int n_in,
                              void* d_out, int out_size, void* d_ws, size_t ws_size,
                              hipStream_t stream) {
    const float* spike = (const float*)d_in[0];   // [256][700][250]
    const float* W_hid = (const float*)d_in[1];   // [1024][700]
    const float* W_out = (const float*)d_in[2];   // [20][1024]
    const float* hs0   = (const float*)d_in[3];   // [256][1024]
    const float* hv0   = (const float*)d_in[4];
    const float* os0   = (const float*)d_in[5];   // [256][20]
    const float* ov0   = (const float*)d_in[6];
    float* outp = (float*)d_out;                  // [256][20]

    char* ws = (char*)d_ws;
    float* Wt     = (float*)(ws);                               // 2,867,200 B
    float* WoT    = (float*)(ws + 2867200);                     //    81,920 B
    u64*   bits   = (u64*)  (ws + 2949120);                     // 6,144,000 B
    u64*   hsbits = (u64*)  (ws + 9093120);                     // 8,192,000 B
    float* Iout   = (float*)(ws + 17285120);                    // 5,120,000 B

    prep_weights<<<2880, 256, 0, stream>>>(W_hid, W_out, Wt, WoT);
    prep_bits<<<1024, 256, 0, stream>>>(spike, bits);
    hidden_kernel<<<B, 1024, 0, stream>>>(bits, Wt, hs0, hv0, hsbits);
    out_currents<<<16000, 256, 0, stream>>>(hsbits, WoT, Iout);
    out_scan<<<20, 256, 0, stream>>>(Iout, os0, ov0, outp);
}